// Round 11
// baseline (118.333 us; speedup 1.0000x reference)
//
#include <hip/hip_runtime.h>
#include <hip/hip_bf16.h>
#include <stdint.h>

// Problem constants
#define NROWS 8192
#define FDIM 256
#define MCOLS 20000
#define NT32 625           // 20000 / 32, exact -> no tail masking
#define MSPLIT 16
#define NCLS 1000
#define LOG2E 1.44269504088896f
#define LN2   0.69314718055994f

// ws layout (bytes), total ~15.5 MB:
//   Mb   bf16 memory          : [0, 10240000)
//   Fb   bf16 box*5*log2e     : [10240000, 14434304)
//   wsel weighted sel logits  : [14434304, 14467072)
//   pm   partial max [16][N]  : [14467072, 14991360)
//   ps   partial sum [16][N]  : [14991360, 15515648)
//   bpart block partials      : [15515648, 15515776)

typedef short short8 __attribute__((ext_vector_type(8)));
typedef float f32x16 __attribute__((ext_vector_type(16)));

typedef __attribute__((address_space(3))) unsigned int lds_u32;
typedef const __attribute__((address_space(1))) unsigned int glb_u32;

__device__ __forceinline__ float ex2(float x) {   // raw v_exp_f32 (2^x), no ocml wrapper
    float r;
    asm("v_exp_f32 %0, %1" : "=v"(r) : "v"(x));
    return r;
}

__device__ __forceinline__ unsigned short f2bf(float x) {
    unsigned u = __float_as_uint(x);
    unsigned r = (u + 0x7FFFu + ((u >> 16) & 1u)) >> 16;   // RNE
    return (unsigned short)r;
}

// max of 16-vector via 3-ary nesting (clang can fuse to v_max3_f32)
__device__ __forceinline__ float vmax16(f32x16 v) {
    float x0 = fmaxf(fmaxf(v[0],  v[1]),  v[2]);
    float x1 = fmaxf(fmaxf(v[3],  v[4]),  v[5]);
    float x2 = fmaxf(fmaxf(v[6],  v[7]),  v[8]);
    float x3 = fmaxf(fmaxf(v[9],  v[10]), v[11]);
    float x4 = fmaxf(fmaxf(v[12], v[13]), v[14]);
    float x5 = fmaxf(fmaxf(x0, x1), x2);
    float x6 = fmaxf(fmaxf(x3, x4), v[15]);
    return fmaxf(x5, x6);
}

__global__ void conv_kernel(const float* __restrict__ in, unsigned short* __restrict__ out,
                            int n4, float scale) {
    int idx = blockIdx.x * blockDim.x + threadIdx.x;
    if (idx >= n4) return;
    float4 v = ((const float4*)in)[idx];
    ushort4 o;
    o.x = f2bf(v.x * scale); o.y = f2bf(v.y * scale);
    o.z = f2bf(v.z * scale); o.w = f2bf(v.w * scale);
    ((ushort4*)out)[idx] = o;
}

// Selected logits: wsel[i] = 5 * sum_d d * dot(F[i], Mem[trace[label_i][d]]), fp32-exact,
// natural-log domain (independent of the exp2 trick in lse_gemm).
__global__ void sel_kernel(const int* __restrict__ gt, const float* __restrict__ F,
                           const float* __restrict__ Mem, const int* __restrict__ trace,
                           float* __restrict__ wsel) {
    int lane = threadIdx.x & 63, wid = threadIdx.x >> 6;
    int i = blockIdx.x * 4 + wid;
    int label = gt[i];
    float w = 0.0f;
    if (label >= 0 && label < NCLS) {
        float4 fv = ((const float4*)(F + (size_t)i * FDIM))[lane];
        #pragma unroll
        for (int d = 1; d <= 3; ++d) {
            int tr = trace[label * 4 + d];
            float4 mv = ((const float4*)(Mem + (size_t)tr * FDIM))[lane];
            float dot = fv.x*mv.x + fv.y*mv.y + fv.z*mv.z + fv.w*mv.w;
            #pragma unroll
            for (int off = 32; off >= 1; off >>= 1) dot += __shfl_xor(dot, off, 64);
            w += (float)d * dot;
        }
    }
    if (lane == 0) wsel[i] = w * 5.0f;   // 1/T
}

// Fused GEMM + online log2-sum-exp2 partials -- swapped-operand 32x32x16,
// 64 ROWS PER WAVE: two A-sets (a_lo in VGPRs, a_hi pinned to AGPRs via "+a"
// inline-asm -- MFMA reads A operands directly from AGPRs on gfx950), so each
// ds_read_b128 B-fragment feeds TWO MFMAs -> LDS-read traffic (the R9 binding
// pipe, ~50us/CU) halves to ~25us/CU < the 33.6us MFMA floor.
// Block: 4 waves x 64 rows = 256 rows; grid 16x32 = 512 = exactly 2 blocks/CU.
// B tile (32 cols x 512B) dbuf in LDS, full 5-bit XOR swizzle (0 conflicts),
// LDS dest linear + pre-swizzled global source. R9's 1-barrier dbuf loop.
__global__ __launch_bounds__(256, 2) void lse_gemm(
        const unsigned short* __restrict__ Fb, const unsigned short* __restrict__ Mb,
        float* __restrict__ pm, float* __restrict__ ps) {
    __shared__ __align__(16) char smem[2 * 16384];  // 32 KiB, double-buffer

    const int split  = blockIdx.x;   // 0..15 ; split%8 == XCD id -> L2-resident B chunk
    const int rowblk = blockIdx.y;   // 0..31
    const int tid  = threadIdx.x;
    const int lane = tid & 63, wid = tid >> 6;
    const int r0 = lane & 31;        // A-row within the 32-row half AND B-col (LDS row)
    const int hi = lane >> 5;        // MFMA k-half / D-col-subset selector
    const int rowbase = rowblk * 256 + wid * 64;

    // A fragments (Y-operand), two row-halves:
    //   a_lo: row rowbase + r0        (VGPR-pinned)
    //   a_hi: row rowbase + 32 + r0   (AGPR-pinned; MFMA consumes AGPRs directly)
    // k-slice per kk: kk*16 + hi*8 .. +8
    short8 al[16], ah[16];
    #pragma unroll
    for (int kk = 0; kk < 16; ++kk) {
        al[kk] = *(const short8*)(Fb + (size_t)(rowbase + r0)      * FDIM + kk * 16 + hi * 8);
        ah[kk] = *(const short8*)(Fb + (size_t)(rowbase + 32 + r0) * FDIM + kk * 16 + hi * 8);
    }
    #pragma unroll
    for (int kk = 0; kk < 16; ++kk) {
        asm volatile("" : "+v"(al[kk]));   // pin: no sink/remat
        asm volatile("" : "+a"(ah[kk]));   // pin INTO AGPRs: outside the arch clamp
    }

    // scalar online state: one row per lane, per half
    float m0 = -3.0e38f, s0 = 0.0f, m1 = -3.0e38f, s1 = 0.0f;

    const int t0 = (split * NT32) / MSPLIT;
    const int t1 = ((split + 1) * NT32) / MSPLIT;   // 39-40 tiles per split

    // Staging: tile = 1024 granules of 16B (32 rows x 512B); 256 threads x 4 calls.
    // LDS dest LINEAR; global source pre-swizzled with FULL 5-bit XOR (o ^ j).
    int srcoff[4];
    #pragma unroll
    for (int c = 0; c < 4; ++c) {
        const int g = (wid * 4 + c) * 64 + lane;
        const int j = g >> 5, o = g & 31;
        srcoff[c] = j * 512 + ((o ^ j) << 4);
    }

#define STAGE(BUF, t)                                                              \
    do {                                                                           \
        const char* srcT = (const char*)Mb + (size_t)(t) * 16384;                  \
        _Pragma("unroll")                                                          \
        for (int c = 0; c < 4; ++c) {                                              \
            __builtin_amdgcn_global_load_lds(                                      \
                (glb_u32*)(srcT + srcoff[c]),                                      \
                (lds_u32*)(smem + (BUF) * 16384 + (wid * 4 + c) * 1024),           \
                16, 0, 0);                                                         \
        }                                                                          \
    } while (0)

    // Read offsets: B-fragment for kk: LDS row r0, granule g=2kk+hi, swizzled g^r0.
    int roff[16];
    #pragma unroll
    for (int kk = 0; kk < 16; ++kk)
        roff[kk] = r0 * 512 + ((((kk << 1) | hi) ^ r0) << 4);

#define BODYC(BUF)                                                                 \
    do {                                                                           \
        f32x16 acc0 = {0,0,0,0,0,0,0,0,0,0,0,0,0,0,0,0};                           \
        f32x16 acc1 = {0,0,0,0,0,0,0,0,0,0,0,0,0,0,0,0};                           \
        __builtin_amdgcn_s_setprio(1);                                             \
        _Pragma("unroll")                                                          \
        for (int kk = 0; kk < 16; ++kk) {                                          \
            short8 b = *(const short8*)(smem + (BUF) * 16384 + roff[kk]);          \
            acc0 = __builtin_amdgcn_mfma_f32_32x32x16_bf16(b, al[kk], acc0, 0, 0, 0); \
            acc1 = __builtin_amdgcn_mfma_f32_32x32x16_bf16(b, ah[kk], acc1, 0, 0, 0); \
        }                                                                          \
        __builtin_amdgcn_s_setprio(0);                                             \
        {                                                                          \
            float nm = fmaxf(vmax16(acc0), m0);                                    \
            float p0 = 0.f, p1 = 0.f, p2 = 0.f, p3 = 0.f;                          \
            _Pragma("unroll")                                                      \
            for (int i = 0; i < 16; i += 4) {                                      \
                p0 += ex2(acc0[i]     - nm); p1 += ex2(acc0[i + 1] - nm);          \
                p2 += ex2(acc0[i + 2] - nm); p3 += ex2(acc0[i + 3] - nm);          \
            }                                                                      \
            s0 = fmaf(s0, ex2(m0 - nm), (p0 + p1) + (p2 + p3));                    \
            m0 = nm;                                                               \
        }                                                                          \
        {                                                                          \
            float nm = fmaxf(vmax16(acc1), m1);                                    \
            float p0 = 0.f, p1 = 0.f, p2 = 0.f, p3 = 0.f;                          \
            _Pragma("unroll")                                                      \
            for (int i = 0; i < 16; i += 4) {                                      \
                p0 += ex2(acc1[i]     - nm); p1 += ex2(acc1[i + 1] - nm);          \
                p2 += ex2(acc1[i + 2] - nm); p3 += ex2(acc1[i + 3] - nm);          \
            }                                                                      \
            s1 = fmaf(s1, ex2(m1 - nm), (p0 + p1) + (p2 + p3));                    \
            m1 = nm;                                                               \
        }                                                                          \
    } while (0)

    STAGE(0, t0);
    __syncthreads();

    int t = t0;
    while (t + 2 <= t1) {
        STAGE(1, t + 1);               // t+1 < t1 inside this loop
        BODYC(0);
        __syncthreads();
        if (t + 2 < t1) STAGE(0, t + 2);
        BODYC(1);
        __syncthreads();
        t += 2;
    }
    if (t < t1) BODYC(0);              // staged by the last iteration

#undef BODYC
#undef STAGE

    // Combine the two hi-halves: lane l and l^32 hold the same row's two
    // 16-col subsets (for both row-halves).
    {
        float om = __shfl_xor(m0, 32, 64);
        float os = __shfl_xor(s0, 32, 64);
        float nm = fmaxf(m0, om);
        float sf = fmaf(s0, ex2(m0 - nm), os * ex2(om - nm));
        if (lane < 32) {
            pm[split * NROWS + rowbase + lane] = nm;
            ps[split * NROWS + rowbase + lane] = sf;
        }
    }
    {
        float om = __shfl_xor(m1, 32, 64);
        float os = __shfl_xor(s1, 32, 64);
        float nm = fmaxf(m1, om);
        float sf = fmaf(s1, ex2(m1 - nm), os * ex2(om - nm));
        if (lane < 32) {
            pm[split * NROWS + rowbase + 32 + lane] = nm;
            ps[split * NROWS + rowbase + 32 + lane] = sf;
        }
    }
}

__global__ void finalize_kernel(const int* __restrict__ gt, const float* __restrict__ wsel,
                                const float* __restrict__ pm, const float* __restrict__ ps,
                                float* __restrict__ bpart) {
    int tid = threadIdx.x;
    int i = blockIdx.x * 256 + tid;
    float mv[MSPLIT];
    float M = -3.0e38f;
    #pragma unroll
    for (int k = 0; k < MSPLIT; ++k) { mv[k] = pm[k * NROWS + i]; M = fmaxf(M, mv[k]); }
    float S = 0.0f;
    #pragma unroll
    for (int k = 0; k < MSPLIT; ++k) S += ps[k * NROWS + i] * ex2(mv[k] - M);
    float lse = (M + __log2f(S)) * LN2;   // back to natural-log domain
    int label = gt[i];
    float per = (label >= 0 && label < NCLS) ? (lse - wsel[i] * (1.0f / 6.0f)) : 0.0f;
    #pragma unroll
    for (int off = 32; off >= 1; off >>= 1) per += __shfl_xor(per, off, 64);
    __shared__ float red[4];
    int lane = tid & 63, wid = tid >> 6;
    if (lane == 0) red[wid] = per;
    __syncthreads();
    if (tid == 0) bpart[blockIdx.x] = red[0] + red[1] + red[2] + red[3];
}

__global__ void sum_kernel(const float* __restrict__ bpart, float* __restrict__ out) {
    int tid = threadIdx.x;
    float v = (tid < 32) ? bpart[tid] : 0.0f;
    #pragma unroll
    for (int off = 32; off >= 1; off >>= 1) v += __shfl_xor(v, off, 64);
    if (tid == 0) out[0] = 0.001f * v;
}

extern "C" void kernel_launch(void* const* d_in, const int* in_sizes, int n_in,
                              void* d_out, int out_size, void* d_ws, size_t ws_size,
                              hipStream_t stream) {
    const int*   gt    = (const int*)d_in[0];
    const float* F     = (const float*)d_in[1];
    const float* Mem   = (const float*)d_in[2];
    const int*   trace = (const int*)d_in[3];
    float* out = (float*)d_out;

    char* w = (char*)d_ws;
    unsigned short* Mb = (unsigned short*)w;
    unsigned short* Fb = (unsigned short*)(w + 10240000);
    float* wsel  = (float*)(w + 14434304);
    float* pm    = (float*)(w + 14467072);
    float* ps    = (float*)(w + 14991360);
    float* bpart = (float*)(w + 15515648);

    conv_kernel<<<dim3((MCOLS * FDIM / 4) / 256), dim3(256), 0, stream>>>(Mem, Mb, MCOLS * FDIM / 4, 1.0f);
    conv_kernel<<<dim3((NROWS * FDIM / 4) / 256), dim3(256), 0, stream>>>(F, Fb, NROWS * FDIM / 4, 5.0f * LOG2E);
    sel_kernel<<<dim3(NROWS / 4), dim3(256), 0, stream>>>(gt, F, Mem, trace, wsel);
    lse_gemm<<<dim3(MSPLIT, NROWS / 256), dim3(256), 0, stream>>>(Fb, Mb, pm, ps);
    finalize_kernel<<<dim3(NROWS / 256), dim3(256), 0, stream>>>(gt, wsel, pm, ps, bpart);
    sum_kernel<<<dim3(1), dim3(64), 0, stream>>>(bpart, out);
}

// Round 12
// 109.447 us; speedup vs baseline: 1.0812x; 1.0812x over previous
//
#include <hip/hip_runtime.h>
#include <hip/hip_bf16.h>
#include <stdint.h>

// Problem constants
#define NROWS 8192
#define FDIM 256
#define MCOLS 20000
#define NT32 625           // 20000 / 32, exact -> no tail masking
#define MSPLIT 16
#define NCLS 1000
#define LOG2E 1.44269504088896f
#define LN2   0.69314718055994f

// ws layout (bytes), total ~15.5 MB:
//   Mb2  bf16 memory, MFMA-fragment order : [0, 10240000)
//   Fb   bf16 box*5*log2e (row-major)     : [10240000, 14434304)
//   wsel weighted sel logits              : [14434304, 14467072)
//   pm   partial max [16][N]              : [14467072, 14991360)
//   ps   partial sum [16][N]              : [14991360, 15515648)
//   bpart block partials                  : [15515648, 15515776)

typedef short short8 __attribute__((ext_vector_type(8)));
typedef float f32x16 __attribute__((ext_vector_type(16)));

typedef __attribute__((address_space(3))) unsigned int lds_u32;
typedef const __attribute__((address_space(1))) unsigned int glb_u32;

__device__ __forceinline__ float ex2(float x) {   // raw v_exp_f32 (2^x), no ocml wrapper
    float r;
    asm("v_exp_f32 %0, %1" : "=v"(r) : "v"(x));
    return r;
}

__device__ __forceinline__ unsigned short f2bf(float x) {
    unsigned u = __float_as_uint(x);
    unsigned r = (u + 0x7FFFu + ((u >> 16) & 1u)) >> 16;   // RNE
    return (unsigned short)r;
}

// max of 16-vector via 3-ary nesting (clang can fuse to v_max3_f32)
__device__ __forceinline__ float vmax16(f32x16 v) {
    float x0 = fmaxf(fmaxf(v[0],  v[1]),  v[2]);
    float x1 = fmaxf(fmaxf(v[3],  v[4]),  v[5]);
    float x2 = fmaxf(fmaxf(v[6],  v[7]),  v[8]);
    float x3 = fmaxf(fmaxf(v[9],  v[10]), v[11]);
    float x4 = fmaxf(fmaxf(v[12], v[13]), v[14]);
    float x5 = fmaxf(fmaxf(x0, x1), x2);
    float x6 = fmaxf(fmaxf(x3, x4), v[15]);
    return fmaxf(x5, x6);
}

// Fb: row-major bf16, scaled by 5*log2(e).
__global__ void conv_kernel(const float* __restrict__ in, unsigned short* __restrict__ out,
                            int n4, float scale) {
    int idx = blockIdx.x * blockDim.x + threadIdx.x;
    if (idx >= n4) return;
    float4 v = ((const float4*)in)[idx];
    ushort4 o;
    o.x = f2bf(v.x * scale); o.y = f2bf(v.y * scale);
    o.z = f2bf(v.z * scale); o.w = f2bf(v.w * scale);
    ((ushort4*)out)[idx] = o;
}

// Mb2: memory in MFMA-fragment order. Granule g = (t*16 + kk)*64 + s (16 B each)
// holds Mem[t*32 + (s&31)][kk*16 + (s>>5)*8 .. +8] as bf16x8. A wave reading
// granules [kk*64 .. kk*64+64) of tile t gets exactly the 32x32x16 B-fragment
// in lane order (lane = s): contiguous, coalesced, swizzle-free.
__global__ void conv_mb2(const float* __restrict__ in, unsigned short* __restrict__ out) {
    int g = blockIdx.x * 256 + threadIdx.x;   // 640000 granules, grid 2500x256 exact
    int s = g & 63, kk = (g >> 6) & 15, t = g >> 10;
    const float* src = in + (size_t)(t * 32 + (s & 31)) * FDIM + kk * 16 + (s >> 5) * 8;
    float4 v0 = ((const float4*)src)[0];
    float4 v1 = ((const float4*)src)[1];
    short8 w;
    w[0] = (short)f2bf(v0.x); w[1] = (short)f2bf(v0.y);
    w[2] = (short)f2bf(v0.z); w[3] = (short)f2bf(v0.w);
    w[4] = (short)f2bf(v1.x); w[5] = (short)f2bf(v1.y);
    w[6] = (short)f2bf(v1.z); w[7] = (short)f2bf(v1.w);
    *(short8*)(out + (size_t)g * 8) = w;
}

// Selected logits: wsel[i] = 5 * sum_d d * dot(F[i], Mem[trace[label_i][d]]), fp32-exact,
// natural-log domain (independent of the exp2 trick in lse_gemm).
__global__ void sel_kernel(const int* __restrict__ gt, const float* __restrict__ F,
                           const float* __restrict__ Mem, const int* __restrict__ trace,
                           float* __restrict__ wsel) {
    int lane = threadIdx.x & 63, wid = threadIdx.x >> 6;
    int i = blockIdx.x * 4 + wid;
    int label = gt[i];
    float w = 0.0f;
    if (label >= 0 && label < NCLS) {
        float4 fv = ((const float4*)(F + (size_t)i * FDIM))[lane];
        #pragma unroll
        for (int d = 1; d <= 3; ++d) {
            int tr = trace[label * 4 + d];
            float4 mv = ((const float4*)(Mem + (size_t)tr * FDIM))[lane];
            float dot = fv.x*mv.x + fv.y*mv.y + fv.z*mv.z + fv.w*mv.w;
            #pragma unroll
            for (int off = 32; off >= 1; off >>= 1) dot += __shfl_xor(dot, off, 64);
            w += (float)d * dot;
        }
    }
    if (lane == 0) wsel[i] = w * 5.0f;   // 1/T
}

// Fused GEMM + online log2-sum-exp2 partials -- swapped-operand 32x32x16 on
// fragment-ordered Mb2: LDS staging is a verbatim linear 16KB copy; LDS reads
// are base+lane*16 with kk*1024 as an IMMEDIATE offset (contiguous 1KB reads,
// bank-ideal, zero address VGPRs). Swizzle machinery (roff/srcoff ~20 VGPRs)
// eliminated -> per-wave total ~122 regs (A+acc in AGPR) -> 4 waves/SIMD at
// __launch_bounds__(256,4). R9's 1-barrier dbuf loop unchanged.
__global__ __launch_bounds__(256, 4) void lse_gemm(
        const unsigned short* __restrict__ Fb, const unsigned short* __restrict__ Mb2,
        float* __restrict__ pm, float* __restrict__ ps) {
    __shared__ __align__(16) char smem[2 * 16384];  // 32 KiB, double-buffer

    const int split  = blockIdx.x;   // 0..15 ; split%8 == XCD id -> L2-resident B chunk
    const int rowblk = blockIdx.y;   // 0..63
    const int tid  = threadIdx.x;
    const int lane = tid & 63, wid = tid >> 6;
    const int r0 = lane & 31;        // A-row within wave AND B-col
    const int hi = lane >> 5;        // k-slice half
    const int rowbase = rowblk * 128 + wid * 32;
    const int l16 = lane << 4;       // lane byte offset within a fragment

    // A fragments (Y-operand): lane holds row (rowbase + r0), k = kk*16 + hi*8 .. +8
    short8 a[16];
    #pragma unroll
    for (int kk = 0; kk < 16; ++kk)
        a[kk] = *(const short8*)(Fb + (size_t)(rowbase + r0) * FDIM + kk * 16 + hi * 8);

    float m = -3.0e38f, s = 0.0f;    // scalar online state: one row per lane

    const int t0 = (split * NT32) / MSPLIT;
    const int t1 = ((split + 1) * NT32) / MSPLIT;   // 39-40 tiles per split

    // Staging: verbatim linear copy of the 16KB fragment-ordered tile chunk.
    // Per thread: 4 x global_load_lds (wave-uniform LDS base + lane*16 by HW;
    // per-lane global src = srcT + lane*16).
#define STAGE(BUF, t)                                                              \
    do {                                                                           \
        const char* srcT = (const char*)Mb2 + (size_t)(t) * 16384 + l16;           \
        _Pragma("unroll")                                                          \
        for (int c = 0; c < 4; ++c) {                                              \
            __builtin_amdgcn_global_load_lds(                                      \
                (glb_u32*)(srcT + (wid * 4 + c) * 1024),                           \
                (lds_u32*)(smem + (BUF) * 16384 + (wid * 4 + c) * 1024),           \
                16, 0, 0);                                                         \
        }                                                                          \
    } while (0)

#define BODYC(BUF)                                                                 \
    do {                                                                           \
        const char* bp = smem + (BUF) * 16384 + l16;                               \
        f32x16 acc = {0,0,0,0,0,0,0,0,0,0,0,0,0,0,0,0};                            \
        __builtin_amdgcn_s_setprio(1);                                             \
        _Pragma("unroll")                                                          \
        for (int kk = 0; kk < 16; ++kk) {                                          \
            short8 b = *(const short8*)(bp + kk * 1024);                           \
            acc = __builtin_amdgcn_mfma_f32_32x32x16_bf16(b, a[kk], acc, 0, 0, 0); \
        }                                                                          \
        __builtin_amdgcn_s_setprio(0);                                             \
        float nm = fmaxf(vmax16(acc), m);                                          \
        float p0 = 0.f, p1 = 0.f, p2 = 0.f, p3 = 0.f;                              \
        _Pragma("unroll")                                                          \
        for (int i = 0; i < 16; i += 4) {                                          \
            p0 += ex2(acc[i]     - nm); p1 += ex2(acc[i + 1] - nm);                \
            p2 += ex2(acc[i + 2] - nm); p3 += ex2(acc[i + 3] - nm);                \
        }                                                                          \
        s = fmaf(s, ex2(m - nm), (p0 + p1) + (p2 + p3));                           \
        m = nm;                                                                    \
    } while (0)

    STAGE(0, t0);
    __syncthreads();

    int t = t0;
    while (t + 2 <= t1) {
        STAGE(1, t + 1);               // t+1 < t1 inside this loop
        BODYC(0);
        __syncthreads();
        if (t + 2 < t1) STAGE(0, t + 2);
        BODYC(1);
        __syncthreads();
        t += 2;
    }
    if (t < t1) BODYC(0);              // staged by the last iteration

#undef BODYC
#undef STAGE

    // Combine the two k-slice halves: lane l and l^32 hold the same row's two
    // 16-col subsets.
    {
        float om = __shfl_xor(m, 32, 64);
        float os = __shfl_xor(s, 32, 64);
        float nm = fmaxf(m, om);
        float sf = fmaf(s, ex2(m - nm), os * ex2(om - nm));
        if (lane < 32) {
            pm[split * NROWS + rowbase + lane] = nm;
            ps[split * NROWS + rowbase + lane] = sf;
        }
    }
}

__global__ void finalize_kernel(const int* __restrict__ gt, const float* __restrict__ wsel,
                                const float* __restrict__ pm, const float* __restrict__ ps,
                                float* __restrict__ bpart) {
    int tid = threadIdx.x;
    int i = blockIdx.x * 256 + tid;
    float mv[MSPLIT];
    float M = -3.0e38f;
    #pragma unroll
    for (int k = 0; k < MSPLIT; ++k) { mv[k] = pm[k * NROWS + i]; M = fmaxf(M, mv[k]); }
    float S = 0.0f;
    #pragma unroll
    for (int k = 0; k < MSPLIT; ++k) S += ps[k * NROWS + i] * ex2(mv[k] - M);
    float lse = (M + __log2f(S)) * LN2;   // back to natural-log domain
    int label = gt[i];
    float per = (label >= 0 && label < NCLS) ? (lse - wsel[i] * (1.0f / 6.0f)) : 0.0f;
    #pragma unroll
    for (int off = 32; off >= 1; off >>= 1) per += __shfl_xor(per, off, 64);
    __shared__ float red[4];
    int lane = tid & 63, wid = tid >> 6;
    if (lane == 0) red[wid] = per;
    __syncthreads();
    if (tid == 0) bpart[blockIdx.x] = red[0] + red[1] + red[2] + red[3];
}

__global__ void sum_kernel(const float* __restrict__ bpart, float* __restrict__ out) {
    int tid = threadIdx.x;
    float v = (tid < 32) ? bpart[tid] : 0.0f;
    #pragma unroll
    for (int off = 32; off >= 1; off >>= 1) v += __shfl_xor(v, off, 64);
    if (tid == 0) out[0] = 0.001f * v;
}

extern "C" void kernel_launch(void* const* d_in, const int* in_sizes, int n_in,
                              void* d_out, int out_size, void* d_ws, size_t ws_size,
                              hipStream_t stream) {
    const int*   gt    = (const int*)d_in[0];
    const float* F     = (const float*)d_in[1];
    const float* Mem   = (const float*)d_in[2];
    const int*   trace = (const int*)d_in[3];
    float* out = (float*)d_out;

    char* w = (char*)d_ws;
    unsigned short* Mb2 = (unsigned short*)w;
    unsigned short* Fb  = (unsigned short*)(w + 10240000);
    float* wsel  = (float*)(w + 14434304);
    float* pm    = (float*)(w + 14467072);
    float* ps    = (float*)(w + 14991360);
    float* bpart = (float*)(w + 15515648);

    conv_mb2<<<dim3(2500), dim3(256), 0, stream>>>(Mem, Mb2);
    conv_kernel<<<dim3((NROWS * FDIM / 4) / 256), dim3(256), 0, stream>>>(F, Fb, NROWS * FDIM / 4, 5.0f * LOG2E);
    sel_kernel<<<dim3(NROWS / 4), dim3(256), 0, stream>>>(gt, F, Mem, trace, wsel);
    lse_gemm<<<dim3(MSPLIT, NROWS / 128), dim3(256), 0, stream>>>(Fb, Mb2, pm, ps);
    finalize_kernel<<<dim3(NROWS / 256), dim3(256), 0, stream>>>(gt, wsel, pm, ps, bpart);
    sum_kernel<<<dim3(1), dim3(64), 0, stream>>>(bpart, out);
}